// Round 12
// baseline (145.958 us; speedup 1.0000x reference)
//
#include <hip/hip_runtime.h>
#include <hip/hip_bf16.h>

typedef __attribute__((ext_vector_type(8))) short short8;
typedef __attribute__((ext_vector_type(4))) float float4v;

#define LOG2E 1.44269504088896340736f

__device__ __forceinline__ unsigned short f2bf(float f) {
    unsigned int u = __float_as_uint(f);
    unsigned int r = (u + 0x7fffu + ((u >> 16) & 1u)) >> 16;  // RNE
    return (unsigned short)r;
}

// ---------------------------------------------------------------------------
// Kernel 1: convert Wk|Wq|Wv (fp32) -> combined bf16 Wb[192][1024]
// ---------------------------------------------------------------------------
__global__ void wconv_kernel(const float* __restrict__ Wk, const float* __restrict__ Wq,
                             const float* __restrict__ Wv, unsigned short* __restrict__ Wb) {
    int i = blockIdx.x * 256 + threadIdx.x;
    if (i >= 192 * 1024) return;
    float v;
    if (i < 65536)       v = Wk[i];
    else if (i < 131072) v = Wq[i - 65536];
    else                 v = Wv[i - 131072];
    Wb[i] = f2bf(v);
}

// ---------------------------------------------------------------------------
// Kernel 2: projection GEMM — R20 verbatim (best measured: proj ~32us).
// M=32, grid 512, coalesced-A via LDS, no DMA, counted vmcnt.
// ---------------------------------------------------------------------------
__global__ __launch_bounds__(256) void proj_kernel(
    const float* __restrict__ x, const unsigned short* __restrict__ Wb,
    unsigned short* __restrict__ qs, unsigned short* __restrict__ ks,
    unsigned short* __restrict__ vT) {
    __shared__ unsigned short Bl[2][12288];  // 2 x 192 rows x 64 ushort, 48 KB
    __shared__ unsigned short Al[2][2048];   // 2 x 32 rows x 64 ushort, 8 KB

    const int tid  = threadIdx.x;
    const int lane = tid & 63;
    const int wave = tid >> 6;
    const int rg   = wave & 1;   // row group (A read)
    const int g    = wave >> 1;  // n-tile group
    const int quad = lane >> 4;
    const int l16  = lane & 15;
    const int t0   = blockIdx.x * 32;

    const int brow_in = lane >> 3;
    const int bchunk  = lane & 7;
    const int bwchunk = bchunk ^ brow_in;

    const int ar = tid >> 3;
    const int ak = tid & 7;
    const float* xsrc = x + (size_t)(t0 + ar) * 1024 + ak * 8;
    const int awoff = ar * 64 + ((ak ^ (ar & 7)) * 8);

    const int arow = rg * 16 + l16;
    const int swz  = l16 & 7;

    float4v acc[6];
#pragma unroll
    for (int n = 0; n < 6; n++) acc[n] = (float4v){0.f, 0.f, 0.f, 0.f};

#define STAGE_LOAD_B(REG, KN)                                                     \
    {                                                                             \
        _Pragma("unroll")                                                         \
        for (int i = 0; i < 6; i++) {                                             \
            const int rowg = (wave * 6 + i) * 8 + brow_in;                        \
            REG[i] = *(const short8*)(Wb + (size_t)rowg * 1024 + (KN) + bchunk * 8); \
        }                                                                         \
    }

#define STAGE_WRITE_B(BUF, REG)                                                   \
    {                                                                             \
        _Pragma("unroll")                                                         \
        for (int i = 0; i < 6; i++)                                               \
            *(short8*)&Bl[BUF][(wave * 6 + i) * 512 + brow_in * 64 + bwchunk * 8] = REG[i]; \
    }

#define LOAD_A_G(F0, F1, KN)                              \
    {                                                     \
        F0 = *(const float4v*)(xsrc + (KN));              \
        F1 = *(const float4v*)(xsrc + (KN) + 4);          \
    }

#define STAGE_WRITE_A(BUF, F0, F1)                        \
    {                                                     \
        short8 w;                                         \
        _Pragma("unroll")                                 \
        for (int j = 0; j < 4; j++) {                     \
            w[j]     = (short)f2bf(F0[j]);                \
            w[4 + j] = (short)f2bf(F1[j]);                \
        }                                                 \
        *(short8*)&Al[BUF][awoff] = w;                    \
    }

    short8 breg[6];
    float4v aS[2][2];
    float4v a0f0, a0f1;
    STAGE_LOAD_B(breg, 0)
    asm volatile("" ::: "memory");
    LOAD_A_G(a0f0, a0f1, 0)
    asm volatile("" ::: "memory");
    LOAD_A_G(aS[1][0], aS[1][1], 64)
    asm volatile("s_waitcnt vmcnt(2)" ::: "memory");
    STAGE_WRITE_B(0, breg)
    STAGE_WRITE_A(0, a0f0, a0f1)
    asm volatile("s_waitcnt lgkmcnt(0)" ::: "memory");
    __builtin_amdgcn_s_barrier();

#pragma unroll
    for (int kt = 0; kt < 16; kt++) {
        __builtin_amdgcn_sched_barrier(0);
        if (kt < 15) {
            STAGE_LOAD_B(breg, (kt + 1) * 64)
        }
        asm volatile("" ::: "memory");
        if (kt < 14) {
            LOAD_A_G(aS[kt & 1][0], aS[kt & 1][1], (kt + 2) * 64)
        }
        asm volatile("" ::: "memory");

        const unsigned short* Bc = Bl[kt & 1];
        const unsigned short* Ac = Al[kt & 1];
#pragma unroll
        for (int kc = 0; kc < 2; kc++) {
            const int coff = ((kc * 4 + quad) ^ swz) * 8;
            const short8 af = *(const short8*)&Ac[arow * 64 + coff];
#pragma unroll
            for (int n = 0; n < 6; n++) {
                const int row = (g * 6 + n) * 16 + l16;
                const short8 bf = *(const short8*)&Bc[row * 64 + coff];
                acc[n] = __builtin_amdgcn_mfma_f32_16x16x32_bf16(af, bf, acc[n], 0, 0, 0);
            }
        }

        if (kt < 15) {
            if (kt < 14) {
                asm volatile("s_waitcnt vmcnt(2)" ::: "memory");
            } else {
                asm volatile("s_waitcnt vmcnt(0)" ::: "memory");
            }
            STAGE_WRITE_B((kt + 1) & 1, breg)
            STAGE_WRITE_A((kt + 1) & 1, aS[(kt + 1) & 1][0], aS[(kt + 1) & 1][1])
            asm volatile("s_waitcnt lgkmcnt(0)" ::: "memory");
            __builtin_amdgcn_s_barrier();
        }
    }
#undef STAGE_LOAD_B
#undef STAGE_WRITE_B
#undef LOAD_A_G
#undef STAGE_WRITE_A

    const int rowD = t0 + rg * 16 + quad * 4;
#pragma unroll
    for (int r = 0; r < 4; r++) {
        const int t = rowD + r;
        const int b = t >> 11, tt = t & 2047;
        if (g == 0) {
#pragma unroll
            for (int n = 0; n < 4; n++)
                ks[(size_t)t * 64 + n * 16 + l16] = f2bf(acc[n][r]);
#pragma unroll
            for (int n = 4; n < 6; n++)
                qs[(size_t)t * 64 + (n - 4) * 16 + l16] = f2bf(acc[n][r] * 0.125f);
        } else {
#pragma unroll
            for (int n = 0; n < 2; n++)
                qs[(size_t)t * 64 + (n + 2) * 16 + l16] = f2bf(acc[n][r] * 0.125f);
#pragma unroll
            for (int n = 2; n < 6; n++)
                vT[(size_t)b * 131072 + (size_t)((n - 2) * 16 + l16) * 2048 + tt] = f2bf(acc[n][r]);
        }
    }
}

// ---------------------------------------------------------------------------
// Kernel 3: causal attention v6 — QBLK=64, WAVE-INDEPENDENT (no merge).
// R22 (QBLK=32) confirmed the line-request model again (attn 33->25us).
// This round: 64 q-rows/block, grid 256 (8b x 32). Wave w owns q-rows
// t0+w*16..+15 and processes ALL keys: causal geometry makes nkb_w = qt+1
// UNIFORM across waves (w*16+15 <= 63 -> same key ceiling), so barriers
// stay aligned and there is no divergence in the s-loop trip count.
// Per-batch super-iters 288 -> 144: staging lines halve again. The merge
// phase disappears: each wave's o[] is complete -> no Of/Ll LDS, no merge
// barriers; per-row 1/lsum via one __shfl (lane quad*4+r holds the total
// for q-row l16==quad*4+r after the 16/32 shfl-xor reduce).
// Why 1 block/CU is OK here (vs R21's proj regression): super-iters are
// coarse (512 staged lines + up to 16 key-block computations between 2
// barriers), and worst-CU lines IMPROVE: old 2-block/CU pair ~9 super-iters
// (~4600 lines) vs new worst qt=31 block 8 super-iters (~4100 lines),
// mean halved. Staging & inner compute loops byte-identical to R22.
// ---------------------------------------------------------------------------
__global__ __launch_bounds__(256) void attn_kernel(
    const unsigned short* __restrict__ qs, const unsigned short* __restrict__ ks,
    const unsigned short* __restrict__ vT, float* __restrict__ out) {
    __shared__ unsigned short Kl[4 * 64 * 72];
    __shared__ unsigned short Vl[64 * 264];
    __shared__ unsigned short P[4][16 * 72];

    const int tid  = threadIdx.x;
    const int lane = tid & 63;
    const int wave = tid >> 6;
    const int quad = lane >> 4;
    const int l16  = lane & 15;
    const int bx   = blockIdx.x;
    const int b    = bx & 7;
    const int qt   = bx >> 3;          // 0..31
    const int t0   = qt * 64;

    const unsigned short* qb = qs + (size_t)b * 131072;
    const unsigned short* kb = ks + (size_t)b * 131072;
    const unsigned short* vb = vT + (size_t)b * 131072;

    const int ksr = tid >> 3;
    const int ksc = (tid & 7) * 8;
    const int vsr = tid >> 5;
    const int vsc = (tid & 31) * 8;

    const int qrow = t0 + wave * 16 + l16;
    const short8 qf0 = *(const short8*)(qb + (size_t)qrow * 64 + quad * 8);
    const short8 qf1 = *(const short8*)(qb + (size_t)qrow * 64 + 32 + quad * 8);

    float4v o[4];
#pragma unroll
    for (int ot = 0; ot < 4; ot++) o[ot] = (float4v){0.f, 0.f, 0.f, 0.f};
    float lpart = 0.f;

    const int nkb  = qt + 1;           // uniform across waves
    const int nsup = (nkb + 3) >> 2;

    for (int s = 0; s < nsup; s++) {
        const int key0 = s * 256;
        __syncthreads();
#pragma unroll
        for (int i2 = 0; i2 < 8; i2++) {
            int kr = key0 + i2 * 32 + ksr; kr = kr < 2047 ? kr : 2047;
            *(short8*)&Kl[(i2 * 32 + ksr) * 72 + ksc] = *(const short8*)(kb + (size_t)kr * 64 + ksc);
        }
#pragma unroll
        for (int i2 = 0; i2 < 8; i2++) {
            const int orow = i2 * 8 + vsr;
            int kc2 = key0 + vsc; kc2 = kc2 < 2040 ? kc2 : 2040;
            *(short8*)&Vl[orow * 264 + vsc] = *(const short8*)(vb + (size_t)orow * 2048 + kc2);
        }
        __syncthreads();

#pragma unroll
        for (int kk = 0; kk < 4; kk++) {
            const int jt = s * 4 + kk;
            if (jt < nkb) {
                const int kbase = kk * 64;
                float4v sv[4];
#pragma unroll
                for (int kt = 0; kt < 4; kt++) {
                    const short8 ka = *(const short8*)&Kl[(kbase + kt * 16 + l16) * 72 + quad * 8];
                    const short8 kc = *(const short8*)&Kl[(kbase + kt * 16 + l16) * 72 + 32 + quad * 8];
                    float4v z = (float4v){0.f, 0.f, 0.f, 0.f};
                    z = __builtin_amdgcn_mfma_f32_16x16x32_bf16(ka, qf0, z, 0, 0, 0);
                    sv[kt] = __builtin_amdgcn_mfma_f32_16x16x32_bf16(kc, qf1, z, 0, 0, 0);
                }
                if (jt == nkb - 1) {
#pragma unroll
                    for (int kt = 0; kt < 4; kt++)
#pragma unroll
                        for (int r = 0; r < 4; r++)
                            if (jt * 64 + kt * 16 + quad * 4 + r > qrow) sv[kt][r] = -1e30f;
                }
#pragma unroll
                for (int kt = 0; kt < 4; kt++) {
                    float p0 = exp2f(sv[kt][0] * LOG2E);
                    float p1 = exp2f(sv[kt][1] * LOG2E);
                    float p2 = exp2f(sv[kt][2] * LOG2E);
                    float p3 = exp2f(sv[kt][3] * LOG2E);
                    lpart += (p0 + p1) + (p2 + p3);
                    unsigned int lo = (unsigned int)f2bf(p0) | ((unsigned int)f2bf(p1) << 16);
                    unsigned int hi = (unsigned int)f2bf(p2) | ((unsigned int)f2bf(p3) << 16);
                    unsigned long long w = ((unsigned long long)hi << 32) | lo;
                    *(unsigned long long*)&P[wave][l16 * 72 + kt * 16 + quad * 4] = w;
                }
#pragma unroll
                for (int kc = 0; kc < 2; kc++) {
                    const short8 pf = *(const short8*)&P[wave][l16 * 72 + kc * 32 + quad * 8];
#pragma unroll
                    for (int ot = 0; ot < 4; ot++) {
                        const short8 vf = *(const short8*)&Vl[(ot * 16 + l16) * 264 + kbase + kc * 32 + quad * 8];
                        o[ot] = __builtin_amdgcn_mfma_f32_16x16x32_bf16(pf, vf, o[ot], 0, 0, 0);
                    }
                }
            }
        }
    }

    // full row-sum for q-row l16 lives in every lane after the 16/32 reduce
    lpart += __shfl_xor(lpart, 16);
    lpart += __shfl_xor(lpart, 32);

    // epilogue: wave-local write, no merge. Row quad*4+r needs lsum of
    // q-row (l16 == quad*4+r) -> lane quad*4+r (its quad is 0).
    const int rowO = t0 + wave * 16 + quad * 4;
#pragma unroll
    for (int r = 0; r < 4; r++) {
        const float inv = 1.0f / __shfl(lpart, quad * 4 + r);
#pragma unroll
        for (int ot = 0; ot < 4; ot++)
            out[(size_t)b * 131072 + (size_t)(rowO + r) * 64 + ot * 16 + l16] = o[ot][r] * inv;
    }
}

// ---------------------------------------------------------------------------
extern "C" void kernel_launch(void* const* d_in, const int* in_sizes, int n_in,
                              void* d_out, int out_size, void* d_ws, size_t ws_size,
                              hipStream_t stream) {
    const float* x  = (const float*)d_in[0];
    const float* Wk = (const float*)d_in[1];
    const float* Wq = (const float*)d_in[2];
    const float* Wv = (const float*)d_in[3];
    float* out = (float*)d_out;

    // Workspace: Wb 384 KB (+pad) | qs 2 MB | ks 2 MB | vT 2 MB
    unsigned short* Wb  = (unsigned short*)d_ws;
    unsigned short* qsb = (unsigned short*)((char*)d_ws + 393216);
    unsigned short* ksb = qsb + 1048576;
    unsigned short* vTb = ksb + 1048576;

    hipLaunchKernelGGL(wconv_kernel, dim3(768), dim3(256), 0, stream, Wk, Wq, Wv, Wb);
    hipLaunchKernelGGL(proj_kernel, dim3(512), dim3(256), 0, stream, x, Wb, qsb, ksb, vTb);
    hipLaunchKernelGGL(attn_kernel, dim3(256), dim3(256), 0, stream, qsb, ksb, vTb, out);
}